// Round 10
// baseline (923.513 us; speedup 1.0000x reference)
//
#include <hip/hip_runtime.h>
#include <math.h>

#define BATCH 8
#define NPTS 4096
#define SSAMP 256
#define KNBR 128
#define GGRID 2025

// fused stage1 block map
#define B_E1 2056
#define B_E2V 2120
#define B_UK 2376
#define B_FF1 2392
#define B_FF2 2900
#define B_TOT 3408

typedef __attribute__((ext_vector_type(8))) short bf16x8;
typedef __attribute__((ext_vector_type(8))) unsigned short u16x8;
typedef __attribute__((ext_vector_type(4))) float f32x4;
#define MFMA16(a, b, c) __builtin_amdgcn_mfma_f32_16x16x32_bf16((a), (b), (c), 0, 0, 0)

__device__ __forceinline__ float lrelu01(float v) { return v > 0.f ? v : 0.01f * v; }
__device__ __forceinline__ unsigned short f2bf(float f) {
    unsigned u = __float_as_uint(f);
    unsigned r = (u + 0x7FFFu + ((u >> 16) & 1u)) >> 16;
    return (unsigned short)r;
}
__device__ __forceinline__ float bf2f(unsigned short h) {
    return __uint_as_float(((unsigned)h) << 16);
}
// hi/lo split: v ~= bf16(hi) + bf16(lo), residual ~2^-17 relative
__device__ __forceinline__ void f2bf2(float v, unsigned short& h, unsigned short& l) {
    h = f2bf(v);
    l = f2bf(v - bf2f(h));
}
__device__ __forceinline__ unsigned long long umax64(unsigned long long a, unsigned long long b) {
    return a > b ? a : b;
}
__device__ __forceinline__ void spin_ge(const int* p, int target) {
    while (__hip_atomic_load(p, __ATOMIC_RELAXED, __HIP_MEMORY_SCOPE_AGENT) < target)
        __builtin_amdgcn_s_sleep(16);
}
__device__ __forceinline__ float aload(const float* p) {
    return __hip_atomic_load((float*)p, __ATOMIC_RELAXED, __HIP_MEMORY_SCOPE_AGENT);
}
__device__ __forceinline__ void astore(float* p, float v) {
    __hip_atomic_store(p, v, __ATOMIC_RELAXED, __HIP_MEMORY_SCOPE_AGENT);
}

// ---------------------------------------------------------------- 0) weight preconvert
// LDS-tiled transpose (64x64 tiles, [64][65] padding): both global sides
// coalesced. 476 blocks. hi+lo planes; We2T col-permute folded into row map.
__global__ void __launch_bounds__(256) preconv_kernel(
    const float* __restrict__ Wc1, const float* __restrict__ Wc2,
    const float* __restrict__ Wc3, const float* __restrict__ We1,
    const float* __restrict__ We2, const float* __restrict__ Wf12,
    const float* __restrict__ Wf22,
    unsigned short* __restrict__ W1T, unsigned short* __restrict__ W2T,
    unsigned short* __restrict__ W3T, unsigned short* __restrict__ We1T,
    unsigned short* __restrict__ We2T, unsigned short* __restrict__ Wf12T,
    unsigned short* __restrict__ Wf22T) {
    __shared__ float tile[64][65];
    int bid = blockIdx.x, t = threadIdx.x;
    int tx = t & 63, ty = t >> 6;
    const float* src; unsigned short* dst;
    int Nsrc, Kout, validK, S, tn, tk; bool we2 = false;
    if (bid < 2)        { src=Wc1;  dst=W1T;  Nsrc=64;   Kout=96;  validK=67;  S=6144;    tn=0;     tk=bid; }
    else if (bid < 4)   { src=Wc2;  dst=W2T;  Nsrc=128;  Kout=64;  validK=64;  S=8192;    tn=bid-2; tk=0; }
    else if (bid < 20)  { int j=bid-4;   src=Wc3;  dst=W3T;  Nsrc=512;  Kout=128; validK=128; S=65536;   tn=j>>1; tk=j&1; }
    else if (bid < 92)  { int j=bid-20;  src=We1;  dst=We1T; Nsrc=512;  Kout=576; validK=515; S=294912;  tn=j/9;  tk=j-(j/9)*9; }
    else if (bid < 348) { int j=bid-92;  src=We2;  dst=We2T; Nsrc=2048; Kout=512; validK=512; S=1048576; tn=j>>3; tk=j&7; we2=true; }
    else if (bid < 412) { int j=bid-348; src=Wf12; dst=Wf12T;Nsrc=512;  Kout=512; validK=512; S=262144;  tn=j>>3; tk=j&7; }
    else                { int j=bid-412; src=Wf22; dst=Wf22T;Nsrc=512;  Kout=512; validK=512; S=262144;  tn=j>>3; tk=j&7; }
    int k0 = tk << 6, n0 = tn << 6;
    int m = we2 ? ((tx < 32) ? (n0 >> 1) + tx : 1024 + (n0 >> 1) + (tx - 32))
                : (n0 + tx);
#pragma unroll
    for (int r = 0; r < 16; ++r) {
        int k = k0 + ty * 16 + r;
        float v = (k < validK) ? src[(size_t)k * Nsrc + m] : 0.f;
        tile[ty * 16 + r][tx] = v;
    }
    __syncthreads();
    int k = k0 + tx;
    if (k < Kout) {
#pragma unroll
        for (int r = 0; r < 16; ++r) {
            int c = ty * 16 + r;
            int nrow = we2 ? (n0 + ((c < 32) ? 2 * c : 2 * (c - 32) + 1)) : (n0 + c);
            float v = tile[tx][c];
            unsigned short h, l; f2bf2(v, h, l);
            size_t o = (size_t)nrow * Kout + k;
            dst[o] = h; dst[S + o] = l;
        }
    }
}

// ---------------------------------------------------------------- fused stage1 (3408 blocks):
//  [0,8)            fps -> prog[b]
//  [8,2056)         pc consumers (forward s) -> encin + cnts[150+rb]
//  [2056,2120)      e1 (waits cnts[150+rb]==128) -> e1h + cnts[rb]
//  [2120,2376)      e2v (waits cnts[rb]==4) -> zacc atomics + cnts[16]
//  [2376,2392)      ukern (waits cnts[16]==256) -> u1/u2 + cnts[17] (release)
//  [2392,2900)      ff1 (waits cnts[17]==16) -> pts atomics + cnts[20+j]
//  [2900,3408)      ff2 (waits cnts[17], cnts[20+j]==4) -> out atomics
// Tail fused to remove the kernel boundary (R2's regression bundled 3 changes;
// this isolates tail-fusion). Deadlock-free: all spins target earlier blocks.
__global__ void __launch_bounds__(256, 3) stage1_kernel(
    const float* __restrict__ pos, float* __restrict__ newpos, int* __restrict__ prog,
    int* __restrict__ cnts,
    const float* __restrict__ Wt, const float* __restrict__ bt,
    const unsigned short* __restrict__ W1T, const unsigned short* __restrict__ W2T,
    const unsigned short* __restrict__ W3T,
    const float* __restrict__ bc1, const float* __restrict__ bc2, const float* __restrict__ bc3,
    unsigned short* __restrict__ encin,
    const unsigned short* __restrict__ We1T, const float* __restrict__ be1,
    unsigned short* __restrict__ e1h,
    const unsigned short* __restrict__ We2T, const float* __restrict__ be2,
    float* __restrict__ zacc,
    const float* __restrict__ Wf11, const float* __restrict__ bf11,
    const float* __restrict__ Wf21, const float* __restrict__ bf21,
    float* __restrict__ u1, float* __restrict__ u2,
    const unsigned short* __restrict__ Wf12T, const float* __restrict__ bf12,
    const float* __restrict__ Wf13, const float* __restrict__ bf13,
    const unsigned short* __restrict__ Wf22T, const float* __restrict__ bf22,
    const float* __restrict__ Wf23, const float* __restrict__ bf23,
    float* __restrict__ pts, float* __restrict__ outv) {
    __shared__ __align__(16) unsigned char smem[53760];
    int blk = blockIdx.x, t = threadIdx.x;
    int wave = t >> 6, lane = t & 63;
    int quad = lane >> 4, l16 = lane & 15;

    if (blk < 8) {
        // ================= FPS producer (DPP-reduce version) =================
        float* pxs = (float*)smem;
        float* pys = (float*)(smem + 16384);
        float* pzs = (float*)(smem + 32768);
        float* npb = (float*)(smem + 49152);
        unsigned long long* rk = (unsigned long long*)(smem + 52224);
        int b = blk;
        const float* P = pos + (size_t)b * NPTS * 3;
        float* np = newpos + (size_t)b * SSAMP * 3;
        float px[16], py[16], pz[16], mind[16];
#pragma unroll
        for (int j = 0; j < 16; ++j) {
            int n = t + 256 * j;
            float X = P[n * 3 + 0], Y = P[n * 3 + 1], Z = P[n * 3 + 2];
            px[j] = X; py[j] = Y; pz[j] = Z;
            pxs[n] = X; pys[n] = Y; pzs[n] = Z;
            mind[j] = 3.402823466e+38f;
        }
        float cx = P[0], cy = P[1], cz = P[2];
        if (t == 0) { npb[0] = cx; npb[1] = cy; npb[2] = cz; }
        __syncthreads();
        for (int s = 1; s < SSAMP; ++s) {
            int p = s & 1;
            unsigned long long k[16];
#pragma unroll
            for (int j = 0; j < 16; ++j) {
                float dx = __fsub_rn(px[j], cx), dy = __fsub_rn(py[j], cy), dz = __fsub_rn(pz[j], cz);
                float d = __fadd_rn(__fadd_rn(__fmul_rn(dx, dx), __fmul_rn(dy, dy)), __fmul_rn(dz, dz));
                mind[j] = fminf(mind[j], d);
                k[j] = ((unsigned long long)__float_as_uint(mind[j]) << 32)
                     | (unsigned)~(unsigned)(t + 256 * j);
            }
#pragma unroll
            for (int st = 8; st > 0; st >>= 1)
#pragma unroll
                for (int j = 0; j < st; ++j) k[j] = umax64(k[j], k[j + st]);
            unsigned khi = (unsigned)(k[0] >> 32), klo = (unsigned)k[0];
#define FPS_DPP_STEP(CTRL)                                                                 \
            {                                                                              \
                unsigned h2 = (unsigned)__builtin_amdgcn_update_dpp(0, (int)khi, CTRL, 0xF, 0xF, true); \
                unsigned l2 = (unsigned)__builtin_amdgcn_update_dpp(0, (int)klo, CTRL, 0xF, 0xF, true); \
                bool tk = (h2 > khi) || ((h2 == khi) && (l2 > klo));                       \
                khi = tk ? h2 : khi; klo = tk ? l2 : klo;                                  \
            }
            FPS_DPP_STEP(0xB1)
            FPS_DPP_STEP(0x4E)
            FPS_DPP_STEP(0x141)
            FPS_DPP_STEP(0x140)
            FPS_DPP_STEP(0x142)
            FPS_DPP_STEP(0x143)
#undef FPS_DPP_STEP
            unsigned shi = (unsigned)__builtin_amdgcn_readlane((int)khi, 63);
            unsigned slo = (unsigned)__builtin_amdgcn_readlane((int)klo, 63);
            if (lane == 0) rk[p * 4 + wave] = ((unsigned long long)shi << 32) | slo;
            __syncthreads();
            unsigned long long k0 = rk[p * 4 + 0], k1 = rk[p * 4 + 1];
            unsigned long long k2 = rk[p * 4 + 2], k3 = rk[p * 4 + 3];
            unsigned long long bk = umax64(umax64(k0, k1), umax64(k2, k3));
            int nx = (int)(~(unsigned)(bk & 0xFFFFFFFFull));
            cx = pxs[nx]; cy = pys[nx]; cz = pzs[nx];
            if (t == 0) {
                npb[s * 3 + 0] = cx;
                npb[s * 3 + 1] = cy;
                npb[s * 3 + 2] = cz;
            }
            if ((s & 7) == 7) {
                if (t < 24) astore(&np[(s - 7) * 3 + t], npb[(s - 7) * 3 + t]);
                if (t == 0 && s >= 15)
                    __hip_atomic_store(&prog[b], s - 8, __ATOMIC_RELAXED, __HIP_MEMORY_SCOPE_AGENT);
            }
        }
        __syncthreads();
        if (t == 0)
            __hip_atomic_store(&prog[b], 255, __ATOMIC_RELAXED, __HIP_MEMORY_SCOPE_AGENT);
        return;
    }

    if (blk < B_E1) {
        // ================= pointconv consumer (b,s) =================
        unsigned short* featl = (unsigned short*)smem;
        unsigned short* h2    = (unsigned short*)smem;
        unsigned short* h1    = (unsigned short*)(smem + 34816);
        float* mred = (float*)(smem + 34816);
        int*   vld  = (int*)(smem + 53248);
        int*   wl   = (int*)smem;
        int*   cnt  = (int*)(smem + 2048);
        float* wtb  = (float*)(smem + 26624);

        int cons = blk - 8;
        int s = cons >> 3, b = cons & 7;
        int bs = b * 256 + s;

        if (t == 0) spin_ge(&prog[b], s);
        __syncthreads();
        float q0 = aload(&newpos[(size_t)bs * 3 + 0]);
        float q1 = aload(&newpos[(size_t)bs * 3 + 1]);
        float q2 = aload(&newpos[(size_t)bs * 3 + 2]);

        const float* P = pos + (size_t)b * NPTS * 3;
        {
            int base = 0;
            for (int c = 0; c < 16 && base < KNBR; ++c) {
                int n = wave * 1024 + c * 64 + lane;
                float dx = __fsub_rn(P[n * 3 + 0], q0);
                float dy = __fsub_rn(P[n * 3 + 1], q1);
                float dz = __fsub_rn(P[n * 3 + 2], q2);
                float d2 = __fadd_rn(__fadd_rn(__fmul_rn(dx, dx), __fmul_rn(dy, dy)), __fmul_rn(dz, dz));
                bool in = (d2 <= 0.04f);
                unsigned long long mask = __ballot(in);
                if (in) {
                    int p = base + __popcll(mask & ((1ull << lane) - 1ull));
                    if (p < KNBR) wl[wave * 128 + p] = n;
                }
                base += __popcll(mask);
            }
            if (lane == 0) cnt[wave] = base < KNBR ? base : KNBR;
        }
        __syncthreads();
        {
            int c0 = cnt[0], c1 = cnt[1], c2 = cnt[2], c3 = cnt[3];
            if (t < 128) {
                int idx = -1, r = t;
                if (r < c0) idx = wl[r];
                else {
                    r -= c0;
                    if (r < c1) idx = wl[128 + r];
                    else {
                        r -= c1;
                        if (r < c2) idx = wl[256 + r];
                        else { r -= c2; if (r < c3) idx = wl[384 + r]; }
                    }
                }
                vld[t] = idx;
            }
            if (t < 192) wtb[t] = Wt[t];
            else wtb[t] = bt[t - 192];
        }
        __syncthreads();

        int vbits = 0;
#pragma unroll
        for (int i = 0; i < 2; ++i)
#pragma unroll
            for (int reg = 0; reg < 4; ++reg)
                if (vld[(2 * wave + i) * 16 + quad * 4 + reg] >= 0) vbits |= 1 << (i * 4 + reg);

        {
            int sr = t >> 1, sh = t & 1;
            int n = vld[sr];
            int ns = n < 0 ? 0 : n;
            const float* pp = pos + ((size_t)b * NPTS + ns) * 3;
            float p0 = pp[0], p1 = pp[1], p2 = pp[2];
            unsigned short* frow = &featl[sr * 104];
            u16x8 z8 = {0, 0, 0, 0, 0, 0, 0, 0};
            if (n >= 0) {
#pragma unroll
                for (int g = 0; g < 4; ++g) {
                    u16x8 v8;
#pragma unroll
                    for (int e = 0; e < 8; ++e) {
                        int c = sh * 32 + g * 8 + e;
                        float v = fmaf(p2, wtb[128 + c], fmaf(p1, wtb[64 + c], fmaf(p0, wtb[c], wtb[192 + c])));
                        v8[e] = (unsigned short)f2bf(lrelu01(v));
                    }
                    *(u16x8*)&frow[sh * 32 + g * 8] = v8;
                }
            } else {
#pragma unroll
                for (int g = 0; g < 4; ++g) *(u16x8*)&frow[sh * 32 + g * 8] = z8;
            }
            if (sh == 1) {
                u16x8 dv = z8;
                if (n >= 0) {
                    dv[0] = (unsigned short)f2bf(__fsub_rn(p0, q0));
                    dv[1] = (unsigned short)f2bf(__fsub_rn(p1, q1));
                    dv[2] = (unsigned short)f2bf(__fsub_rn(p2, q2));
                }
                *(u16x8*)&frow[64] = dv;
                *(u16x8*)&frow[72] = z8;
                *(u16x8*)&frow[80] = z8;
                *(u16x8*)&frow[88] = z8;
            }
        }
        __syncthreads();

        {
            f32x4 acc[2][4];
#pragma unroll
            for (int i = 0; i < 2; ++i)
#pragma unroll
                for (int nt = 0; nt < 4; ++nt) acc[i][nt] = (f32x4){0.f, 0.f, 0.f, 0.f};
#pragma unroll
            for (int ks = 0; ks < 3; ++ks) {
                bf16x8 afr[2];
#pragma unroll
                for (int i = 0; i < 2; ++i)
                    afr[i] = *(const bf16x8*)&featl[((2 * wave + i) * 16 + l16) * 104 + ks * 32 + quad * 8];
#pragma unroll
                for (int nt = 0; nt < 4; ++nt) {
                    const unsigned short* wp = W1T + (nt * 16 + l16) * 96 + ks * 32 + quad * 8;
                    bf16x8 bh = *(const bf16x8*)wp;
                    bf16x8 bl = *(const bf16x8*)(wp + 6144);
                    acc[0][nt] = MFMA16(afr[0], bh, acc[0][nt]);
                    acc[1][nt] = MFMA16(afr[1], bh, acc[1][nt]);
                    acc[0][nt] = MFMA16(afr[0], bl, acc[0][nt]);
                    acc[1][nt] = MFMA16(afr[1], bl, acc[1][nt]);
                }
            }
#pragma unroll
            for (int i = 0; i < 2; ++i)
#pragma unroll
                for (int nt = 0; nt < 4; ++nt) {
                    int col = nt * 16 + l16;
                    float bias = bc1[col];
#pragma unroll
                    for (int reg = 0; reg < 4; ++reg) {
                        int row = (2 * wave + i) * 16 + quad * 4 + reg;
                        h1[row * 72 + col] = f2bf(lrelu01(acc[i][nt][reg] + bias));
                    }
                }
        }
        __syncthreads();

        {
            f32x4 acc[2][8];
#pragma unroll
            for (int i = 0; i < 2; ++i)
#pragma unroll
                for (int nt = 0; nt < 8; ++nt) acc[i][nt] = (f32x4){0.f, 0.f, 0.f, 0.f};
#pragma unroll
            for (int ks = 0; ks < 2; ++ks) {
                bf16x8 afr[2];
#pragma unroll
                for (int i = 0; i < 2; ++i)
                    afr[i] = *(const bf16x8*)&h1[((2 * wave + i) * 16 + l16) * 72 + ks * 32 + quad * 8];
#pragma unroll
                for (int nt = 0; nt < 8; ++nt) {
                    const unsigned short* wp = W2T + (nt * 16 + l16) * 64 + ks * 32 + quad * 8;
                    bf16x8 bh = *(const bf16x8*)wp;
                    bf16x8 bl = *(const bf16x8*)(wp + 8192);
                    acc[0][nt] = MFMA16(afr[0], bh, acc[0][nt]);
                    acc[1][nt] = MFMA16(afr[1], bh, acc[1][nt]);
                    acc[0][nt] = MFMA16(afr[0], bl, acc[0][nt]);
                    acc[1][nt] = MFMA16(afr[1], bl, acc[1][nt]);
                }
            }
            __syncthreads();
#pragma unroll
            for (int i = 0; i < 2; ++i)
#pragma unroll
                for (int nt = 0; nt < 8; ++nt) {
                    int col = nt * 16 + l16;
                    float bias = bc2[col];
#pragma unroll
                    for (int reg = 0; reg < 4; ++reg) {
                        int row = (2 * wave + i) * 16 + quad * 4 + reg;
                        h2[row * 136 + col] = f2bf(lrelu01(acc[i][nt][reg] + bias));
                    }
                }
        }
        __syncthreads();

        for (int c3 = 0; c3 < 4; ++c3) {
            f32x4 acc[2][8];
#pragma unroll
            for (int i = 0; i < 2; ++i)
#pragma unroll
                for (int nt = 0; nt < 8; ++nt) acc[i][nt] = (f32x4){0.f, 0.f, 0.f, 0.f};
#pragma unroll
            for (int ks = 0; ks < 4; ++ks) {
                bf16x8 afr[2];
#pragma unroll
                for (int i = 0; i < 2; ++i)
                    afr[i] = *(const bf16x8*)&h2[((2 * wave + i) * 16 + l16) * 136 + ks * 32 + quad * 8];
#pragma unroll
                for (int nt = 0; nt < 8; ++nt) {
                    const unsigned short* wp = W3T + ((size_t)((c3 * 8 + nt) * 16 + l16)) * 128 + ks * 32 + quad * 8;
                    bf16x8 bh = *(const bf16x8*)wp;
                    bf16x8 bl = *(const bf16x8*)(wp + 65536);
                    acc[0][nt] = MFMA16(afr[0], bh, acc[0][nt]);
                    acc[1][nt] = MFMA16(afr[1], bh, acc[1][nt]);
                    acc[0][nt] = MFMA16(afr[0], bl, acc[0][nt]);
                    acc[1][nt] = MFMA16(afr[1], bl, acc[1][nt]);
                }
            }
#pragma unroll
            for (int nt = 0; nt < 8; ++nt) {
                float vmax = -3.402823466e+38f;
#pragma unroll
                for (int i = 0; i < 2; ++i)
#pragma unroll
                    for (int reg = 0; reg < 4; ++reg)
                        if (vbits & (1 << (i * 4 + reg))) vmax = fmaxf(vmax, acc[i][nt][reg]);
                vmax = fmaxf(vmax, __shfl_xor(vmax, 16));
                vmax = fmaxf(vmax, __shfl_xor(vmax, 32));
                if (lane < 16) mred[wave * 512 + (c3 * 8 + nt) * 16 + l16] = vmax;
            }
        }
        __syncthreads();
        unsigned short* erow = encin + (size_t)bs * 576;
        for (int c = t; c < 576; c += 256) {
            unsigned short v;
            if (c < 512) {
                float m4 = fmaxf(fmaxf(mred[c], mred[512 + c]), fmaxf(mred[1024 + c], mred[1536 + c]));
                v = f2bf(lrelu01(m4 + bc3[c]));
            } else if (c < 515) {
                v = f2bf(c == 512 ? q0 : (c == 513 ? q1 : q2));
            } else v = 0;
            erow[c] = v;
        }
        __syncthreads();
        if (t == 0) { __threadfence(); atomicAdd(&cnts[150 + (bs >> 7)], 1); }
        return;
    }

    if (blk < B_UK) {
        // ================= e1 / e2v =================
        unsigned short* As = (unsigned short*)smem;
        bool is_e1 = blk < B_E2V;
        int rb, cb;
        const unsigned short* A;
        const unsigned short* BT;
        int Ka;
        if (is_e1) {
            int j = blk - B_E1; rb = j >> 2; cb = j & 3; A = encin; BT = We1T; Ka = 576;
            if (t == 0) spin_ge(&cnts[150 + rb], 128);
        } else {
            int j = blk - B_E2V; rb = j >> 4; cb = j & 15; A = e1h; BT = We2T; Ka = 512;
            if (t == 0) spin_ge(&cnts[rb], 4);
        }
        int bofs = is_e1 ? 294912 : 1048576;   // lo-plane offset (elements)
        __syncthreads();
        __threadfence();   // acquire bulk normal-store data (encin / e1h)
        int row0 = rb * 128, col0 = cb * 128;
        f32x4 acc[2][8];
#pragma unroll
        for (int i = 0; i < 2; ++i)
#pragma unroll
            for (int nt = 0; nt < 8; ++nt) acc[i][nt] = (f32x4){0.f, 0.f, 0.f, 0.f};
        int nk = Ka >> 6;
        int sr = t >> 1, sh = t & 1;
        const unsigned short* Arow = A + (size_t)(row0 + sr) * Ka + sh * 32;
        for (int ks = 0; ks < nk; ++ks) {
            u16x8 av[4];
#pragma unroll
            for (int j2 = 0; j2 < 4; ++j2) av[j2] = *(const u16x8*)(Arow + ks * 64 + j2 * 8);
            __syncthreads();
#pragma unroll
            for (int j2 = 0; j2 < 4; ++j2) *(u16x8*)&As[sr * 72 + sh * 32 + j2 * 8] = av[j2];
            __syncthreads();
#pragma unroll
            for (int ks2 = 0; ks2 < 2; ++ks2) {
                bf16x8 afr0 = *(const bf16x8*)&As[((2 * wave) * 16 + l16) * 72 + ks2 * 32 + quad * 8];
                bf16x8 afr1 = *(const bf16x8*)&As[((2 * wave + 1) * 16 + l16) * 72 + ks2 * 32 + quad * 8];
#pragma unroll
                for (int nt = 0; nt < 8; ++nt) {
                    const unsigned short* wp = BT + (size_t)(col0 + nt * 16 + l16) * Ka + ks * 64 + ks2 * 32 + quad * 8;
                    bf16x8 bh = *(const bf16x8*)wp;
                    bf16x8 bl = *(const bf16x8*)(wp + bofs);
                    acc[0][nt] = MFMA16(afr0, bh, acc[0][nt]);
                    acc[1][nt] = MFMA16(afr1, bh, acc[1][nt]);
                    acc[0][nt] = MFMA16(afr0, bl, acc[0][nt]);
                    acc[1][nt] = MFMA16(afr1, bl, acc[1][nt]);
                }
            }
        }
        if (is_e1) {
#pragma unroll
            for (int i = 0; i < 2; ++i)
#pragma unroll
                for (int nt = 0; nt < 8; ++nt) {
                    int col = col0 + nt * 16 + l16;
                    float bv = be1[col];
#pragma unroll
                    for (int reg = 0; reg < 4; ++reg) {
                        int row = row0 + (2 * wave + i) * 16 + quad * 4 + reg;
                        e1h[(size_t)row * 512 + col] = f2bf(lrelu01(acc[i][nt][reg] + bv));
                    }
                }
            __syncthreads();
            if (t == 0) { __threadfence(); atomicAdd(&cnts[rb], 1); }
        } else {
            int b = row0 >> 8;
#pragma unroll
            for (int nt = 0; nt < 8; ++nt) {
                int colp = col0 + nt * 16 + l16;
                int c2 = colp >> 1;
                int srcc = (colp & 1) ? 1024 + c2 : c2;
                float bv = be2[srcc];
                float num = 0.f, den = 0.f;
#pragma unroll
                for (int i = 0; i < 2; ++i)
#pragma unroll
                    for (int reg = 0; reg < 4; ++reg) {
                        float val = acc[i][nt][reg] + bv;
                        float par = __shfl_xor(val, 1, 64);
                        float d = expf(-0.5f * par);
                        num += val * d;
                        den += d;
                    }
                num += __shfl_xor(num, 16, 64); den += __shfl_xor(den, 16, 64);
                num += __shfl_xor(num, 32, 64); den += __shfl_xor(den, 32, 64);
                if (quad == 0 && !(l16 & 1)) {
                    atomicAdd(&zacc[((b << 10) + c2) * 2 + 0], num);
                    atomicAdd(&zacc[((b << 10) + c2) * 2 + 1], den);
                }
            }
            __syncthreads();
            if (t == 0) atomicAdd(&cnts[16], 1);
        }
        return;
    }

    if (blk < B_FF1) {
        // ================= ukern =================
        float* zt = (float*)smem;
        float* red = (float*)(smem + 32768);
        int j = blk - B_UK;
        int dec = j >> 3, cb = j & 7;
        const float* W = dec ? Wf21 : Wf11;
        const float* bias = dec ? bf21 : bf11;
        float* u = dec ? u2 : u1;
        if (t == 0) spin_ge(&cnts[16], 256);
        __syncthreads();
#pragma unroll
        for (int i = 0; i < 32; ++i) {
            int o = t + i * 256;
            float num = aload(&zacc[o * 2 + 0]);
            float den = aload(&zacc[o * 2 + 1]);
            zt[(o & 1023) * 8 + (o >> 10)] = num / den;
        }
        __syncthreads();
        int c64 = t & 63, kc = t >> 6;
        int co = cb * 64 + c64;
        float acc[8];
#pragma unroll
        for (int r = 0; r < 8; ++r) acc[r] = 0.f;
        for (int i = 0; i < 256; ++i) {
            int ci = kc * 256 + i;
            float w = W[(size_t)ci * 512 + co];
            const float4* zp = (const float4*)&zt[ci * 8];
            float4 z0 = zp[0], z1 = zp[1];
            acc[0] = fmaf(z0.x, w, acc[0]); acc[1] = fmaf(z0.y, w, acc[1]);
            acc[2] = fmaf(z0.z, w, acc[2]); acc[3] = fmaf(z0.w, w, acc[3]);
            acc[4] = fmaf(z1.x, w, acc[4]); acc[5] = fmaf(z1.y, w, acc[5]);
            acc[6] = fmaf(z1.z, w, acc[6]); acc[7] = fmaf(z1.w, w, acc[7]);
        }
#pragma unroll
        for (int r = 0; r < 8; ++r) red[(kc * 64 + c64) * 8 + r] = acc[r];
        __syncthreads();
        if (kc == 0) {
#pragma unroll
            for (int r = 0; r < 8; ++r) {
                float v = red[(0 * 64 + c64) * 8 + r] + red[(1 * 64 + c64) * 8 + r]
                        + red[(2 * 64 + c64) * 8 + r] + red[(3 * 64 + c64) * 8 + r] + bias[co];
                astore(&u[r * 512 + co], v);
            }
        }
        __syncthreads();
        if (t == 0) { __threadfence(); atomicAdd(&cnts[17], 1); }   // release u1/u2
        return;
    }

    // ================= ff1 / ff2 (folds, fused) =================
    {
        unsigned short* As  = (unsigned short*)smem;                 // 18432 (hi)
        unsigned short* Asl = (unsigned short*)(smem + 18432);       // 18432 (lo)
        float* sW  = (float*)(smem + 36864);                         // [3][512]
        float* sU  = (float*)(smem + 43008);                         // [2][512]
        float* sP  = (float*)(smem + 47104);                         // [128*3]
        float* sB  = (float*)(smem + 48640);                         // [128]
        float* sRC = (float*)(smem + 49152);                         // [128][4]
        int dec = blk < B_FF2 ? 0 : 1;
        int idx0 = blk - (dec ? B_FF2 : B_FF1);
        int j = idx0 >> 2, cc = idx0 & 3;
        const float* u = dec ? u2 : u1;
        const float* Wfold = dec ? Wf21 : Wf11;
        int nExtra = dec ? 3 : 2;
        const unsigned short* WT = dec ? Wf22T : Wf12T;
        const float* bmid = dec ? bf22 : bf12;
        const float* wout = dec ? Wf23 : Wf13;
        const float* bout = dec ? bf23 : bf13;
        float* ov = dec ? outv : pts;
        int row0 = j * 128, col0 = cc * 128;
        int b0 = row0 / 2025;

        // static preloads (raw inputs, safe before any spin)
        for (int idx = t; idx < 1536; idx += 256) {
            int r = idx >> 9, c = idx & 511;
            sW[r * 512 + c] = (r < nExtra) ? Wfold[(size_t)(1024 + r) * 512 + c] : 0.f;
        }
        for (int idx = t; idx < 384; idx += 256) sP[idx] = wout[col0 * 3 + idx];
        if (t < 128) sB[t] = bmid[col0 + t];
        if (dec == 0 && t < 128) {
            int rg = row0 + t; if (rg > 16199) rg = 16199;
            int b = rg / 2025, g = rg - b * 2025;
            int i = g / 45, jj = g - i * 45;
            sRC[t * 4 + 0] = (jj == 44) ? 0.3f : (float)(-0.3 + jj * (0.6 / 44.0));
            sRC[t * 4 + 1] = (i == 44) ? 0.3f : (float)(-0.3 + i * (0.6 / 44.0));
            sRC[t * 4 + 2] = 0.f;
            sRC[t * 4 + 3] = __int_as_float(b - b0);
        }

        if (t == 0) {
            spin_ge(&cnts[17], 16);                   // u1/u2 ready (ukern release)
            if (dec) spin_ge(&cnts[20 + j], 4);       // pts ready (ff1 release)
        }
        __syncthreads();
        __threadfence();   // acquire u (astore) + pts (atomicAdd)

        for (int idx = t; idx < 1024; idx += 256) {
            int rb = idx >> 9;
            int bb = b0 + rb; if (bb > 7) bb = 7;
            sU[rb * 512 + (idx & 511)] = aload(&u[bb * 512 + (idx & 511)]);
        }
        if (dec && t < 128) {
            int rg = row0 + t; if (rg > 16199) rg = 16199;
            int b = rg / 2025;
            sRC[t * 4 + 0] = aload(&pts[rg * 3 + 0]);
            sRC[t * 4 + 1] = aload(&pts[rg * 3 + 1]);
            sRC[t * 4 + 2] = aload(&pts[rg * 3 + 2]);
            sRC[t * 4 + 3] = __int_as_float(b - b0);
        }
        __syncthreads();

        float proj[2][4][3];
#pragma unroll
        for (int i = 0; i < 2; ++i)
#pragma unroll
            for (int r = 0; r < 4; ++r) { proj[i][r][0] = 0.f; proj[i][r][1] = 0.f; proj[i][r][2] = 0.f; }

        int sr = t >> 1, sh = t & 1;
        float4 rc = *(const float4*)&sRC[sr * 4];
        int ubi = __float_as_int(rc.w);
        const float* up = sU + ubi * 512;
        f32x4 acc[2][8];
#pragma unroll
        for (int i = 0; i < 2; ++i)
#pragma unroll
            for (int nt = 0; nt < 8; ++nt) acc[i][nt] = (f32x4){0.f, 0.f, 0.f, 0.f};
        for (int ks = 0; ks < 8; ++ks) {
            __syncthreads();
            {
                int cbase = ks * 64 + sh * 32;
                const float4* w0p = (const float4*)&sW[cbase];
                const float4* w1p = (const float4*)&sW[512 + cbase];
                const float4* w2p = (const float4*)&sW[1024 + cbase];
                const float4* uup = (const float4*)&up[cbase];
#pragma unroll
                for (int g4 = 0; g4 < 8; ++g4) {
                    float4 w0 = w0p[g4], w1 = w1p[g4], w2 = w2p[g4], uu = uup[g4];
                    float v0 = fmaf(rc.z, w2.x, fmaf(rc.y, w1.x, fmaf(rc.x, w0.x, uu.x)));
                    float v1 = fmaf(rc.z, w2.y, fmaf(rc.y, w1.y, fmaf(rc.x, w0.y, uu.y)));
                    float v2 = fmaf(rc.z, w2.z, fmaf(rc.y, w1.z, fmaf(rc.x, w0.z, uu.z)));
                    float v3 = fmaf(rc.z, w2.w, fmaf(rc.y, w1.w, fmaf(rc.x, w0.w, uu.w)));
                    float r0 = fmaxf(v0, 0.f), r1 = fmaxf(v1, 0.f);
                    float r2 = fmaxf(v2, 0.f), r3 = fmaxf(v3, 0.f);
                    unsigned short h0, l0, h1s, l1s, h2s, l2s, h3s, l3s;
                    f2bf2(r0, h0, l0); f2bf2(r1, h1s, l1s);
                    f2bf2(r2, h2s, l2s); f2bf2(r3, h3s, l3s);
                    uint2 pkh, pkl;
                    pkh.x = (unsigned)h0 | ((unsigned)h1s << 16);
                    pkh.y = (unsigned)h2s | ((unsigned)h3s << 16);
                    pkl.x = (unsigned)l0 | ((unsigned)l1s << 16);
                    pkl.y = (unsigned)l2s | ((unsigned)l3s << 16);
                    *(uint2*)&As[sr * 72 + sh * 32 + g4 * 4] = pkh;
                    *(uint2*)&Asl[sr * 72 + sh * 32 + g4 * 4] = pkl;
                }
            }
            __syncthreads();
#pragma unroll
            for (int ks2 = 0; ks2 < 2; ++ks2) {
                bf16x8 ah0 = *(const bf16x8*)&As[((2 * wave) * 16 + l16) * 72 + ks2 * 32 + quad * 8];
                bf16x8 ah1 = *(const bf16x8*)&As[((2 * wave + 1) * 16 + l16) * 72 + ks2 * 32 + quad * 8];
                bf16x8 al0 = *(const bf16x8*)&Asl[((2 * wave) * 16 + l16) * 72 + ks2 * 32 + quad * 8];
                bf16x8 al1 = *(const bf16x8*)&Asl[((2 * wave + 1) * 16 + l16) * 72 + ks2 * 32 + quad * 8];
#pragma unroll
                for (int nt = 0; nt < 8; ++nt) {
                    const unsigned short* wp = WT + (size_t)(col0 + nt * 16 + l16) * 512 + ks * 64 + ks2 * 32 + quad * 8;
                    bf16x8 bh = *(const bf16x8*)wp;
                    bf16x8 bl = *(const bf16x8*)(wp + 262144);
                    acc[0][nt] = MFMA16(ah0, bh, acc[0][nt]);
                    acc[1][nt] = MFMA16(ah1, bh, acc[1][nt]);
                    acc[0][nt] = MFMA16(ah0, bl, acc[0][nt]);
                    acc[1][nt] = MFMA16(ah1, bl, acc[1][nt]);
                    acc[0][nt] = MFMA16(al0, bh, acc[0][nt]);
                    acc[1][nt] = MFMA16(al1, bh, acc[1][nt]);
                }
            }
        }
#pragma unroll
        for (int i = 0; i < 2; ++i)
#pragma unroll
            for (int nt = 0; nt < 8; ++nt) {
                int lc = nt * 16 + l16;
                float bv = sB[lc];
                float w0 = sP[lc * 3 + 0], w1 = sP[lc * 3 + 1], w2 = sP[lc * 3 + 2];
#pragma unroll
                for (int reg = 0; reg < 4; ++reg) {
                    float h = fmaxf(acc[i][nt][reg] + bv, 0.f);
                    proj[i][reg][0] = fmaf(h, w0, proj[i][reg][0]);
                    proj[i][reg][1] = fmaf(h, w1, proj[i][reg][1]);
                    proj[i][reg][2] = fmaf(h, w2, proj[i][reg][2]);
                }
            }
        float o0 = (cc == 0) ? bout[0] : 0.f;
        float o1 = (cc == 0) ? bout[1] : 0.f;
        float o2 = (cc == 0) ? bout[2] : 0.f;
#pragma unroll
        for (int i = 0; i < 2; ++i)
#pragma unroll
            for (int reg = 0; reg < 4; ++reg) {
                float p0 = proj[i][reg][0], p1 = proj[i][reg][1], p2 = proj[i][reg][2];
#pragma unroll
                for (int m = 1; m < 16; m <<= 1) {
                    p0 += __shfl_xor(p0, m, 64);
                    p1 += __shfl_xor(p1, m, 64);
                    p2 += __shfl_xor(p2, m, 64);
                }
                if (l16 == 0) {
                    int row = row0 + (2 * wave + i) * 16 + quad * 4 + reg;
                    if (row < 16200) {
                        atomicAdd(&ov[row * 3 + 0], p0 + o0);
                        atomicAdd(&ov[row * 3 + 1], p1 + o1);
                        atomicAdd(&ov[row * 3 + 2], p2 + o2);
                    }
                }
            }
        if (dec == 0) {
            __syncthreads();
            if (t == 0) atomicAdd(&cnts[20 + j], 1);
        }
    }
}

extern "C" void kernel_launch(void* const* d_in, const int* in_sizes, int n_in,
                              void* d_out, int out_size, void* d_ws, size_t ws_size,
                              hipStream_t stream) {
    const float* pos  = (const float*)d_in[0];
    const float* Wt   = (const float*)d_in[1];
    const float* bt   = (const float*)d_in[2];
    const float* Wc1  = (const float*)d_in[3];
    const float* bc1  = (const float*)d_in[4];
    const float* Wc2  = (const float*)d_in[5];
    const float* bc2  = (const float*)d_in[6];
    const float* Wc3  = (const float*)d_in[7];
    const float* bc3  = (const float*)d_in[8];
    const float* We1  = (const float*)d_in[9];
    const float* be1  = (const float*)d_in[10];
    const float* We2  = (const float*)d_in[11];
    const float* be2  = (const float*)d_in[12];
    const float* Wf11 = (const float*)d_in[13];
    const float* bf11 = (const float*)d_in[14];
    const float* Wf12 = (const float*)d_in[15];
    const float* bf12 = (const float*)d_in[16];
    const float* Wf13 = (const float*)d_in[17];
    const float* bf13 = (const float*)d_in[18];
    const float* Wf21 = (const float*)d_in[19];
    const float* bf21 = (const float*)d_in[20];
    const float* Wf22 = (const float*)d_in[21];
    const float* bf22 = (const float*)d_in[22];
    const float* Wf23 = (const float*)d_in[23];
    const float* bf23 = (const float*)d_in[24];
    float* out = (float*)d_out;

    float* wsf = (float*)d_ws;
    size_t off = 0;
    unsigned short* encinh= (unsigned short*)(wsf + off); off += 589824;   // [2048][576] bf16
    unsigned short* e1h   = (unsigned short*)(wsf + off); off += 524288;   // [2048][512] bf16
    float* zacc = wsf + off; off += 16384;     // [8][1024][2]
    float* u1   = wsf + off; off += 4096;
    float* u2   = wsf + off; off += 4096;
    float* pts  = wsf + off; off += 48600;     // [16200][3] (atomic-accumulated)
    float* newp = wsf + off; off += 6144;      // [B,S,3]
    int*   prog = (int*)(wsf + off); off += 16;
    int*   cnts = (int*)(wsf + off); off += 256;
    // weight planes doubled: hi at [0,N), lo at [N,2N) shorts -> N floats each
    unsigned short* W1T   = (unsigned short*)(wsf + off); off += 6144;
    unsigned short* W2T   = (unsigned short*)(wsf + off); off += 8192;
    unsigned short* W3T   = (unsigned short*)(wsf + off); off += 65536;
    unsigned short* We1T  = (unsigned short*)(wsf + off); off += 294912;
    unsigned short* We2T  = (unsigned short*)(wsf + off); off += 1048576;
    unsigned short* Wf12T = (unsigned short*)(wsf + off); off += 262144;
    unsigned short* Wf22T = (unsigned short*)(wsf + off); off += 262144;

    hipMemsetAsync(prog, 0xFF, 64, stream);
    hipMemsetAsync(cnts, 0x00, 1024, stream);
    hipMemsetAsync(zacc, 0x00, 16384 * 4, stream);
    hipMemsetAsync(pts, 0x00, 48600 * 4, stream);
    hipMemsetAsync(out, 0x00, (size_t)out_size * 4, stream);
    preconv_kernel<<<476, 256, 0, stream>>>(Wc1, Wc2, Wc3, We1, We2, Wf12, Wf22,
                                            W1T, W2T, W3T, We1T, We2T, Wf12T, Wf22T);
    stage1_kernel<<<B_TOT, 256, 0, stream>>>(pos, newp, prog, cnts, Wt, bt, W1T, W2T, W3T,
                                             bc1, bc2, bc3, encinh,
                                             We1T, be1, e1h, We2T, be2, zacc,
                                             Wf11, bf11, Wf21, bf21, u1, u2,
                                             Wf12T, bf12, Wf13, bf13,
                                             Wf22T, bf22, Wf23, bf23, pts, out);
}

// Round 11
// 794.536 us; speedup vs baseline: 1.1623x; 1.1623x over previous
//
#include <hip/hip_runtime.h>
#include <math.h>

#define BATCH 8
#define NPTS 4096
#define SSAMP 256
#define KNBR 128
#define GGRID 2025

typedef __attribute__((ext_vector_type(8))) short bf16x8;
typedef __attribute__((ext_vector_type(8))) unsigned short u16x8;
typedef __attribute__((ext_vector_type(4))) float f32x4;
#define MFMA16(a, b, c) __builtin_amdgcn_mfma_f32_16x16x32_bf16((a), (b), (c), 0, 0, 0)

__device__ __forceinline__ float lrelu01(float v) { return v > 0.f ? v : 0.01f * v; }
__device__ __forceinline__ unsigned short f2bf(float f) {
    unsigned u = __float_as_uint(f);
    unsigned r = (u + 0x7FFFu + ((u >> 16) & 1u)) >> 16;
    return (unsigned short)r;
}
__device__ __forceinline__ float bf2f(unsigned short h) {
    return __uint_as_float(((unsigned)h) << 16);
}
// hi/lo split: v ~= bf16(hi) + bf16(lo), residual ~2^-17 relative
__device__ __forceinline__ void f2bf2(float v, unsigned short& h, unsigned short& l) {
    h = f2bf(v);
    l = f2bf(v - bf2f(h));
}
__device__ __forceinline__ unsigned long long umax64(unsigned long long a, unsigned long long b) {
    return a > b ? a : b;
}
__device__ __forceinline__ void spin_ge(const int* p, int target) {
    while (__hip_atomic_load(p, __ATOMIC_RELAXED, __HIP_MEMORY_SCOPE_AGENT) < target)
        __builtin_amdgcn_s_sleep(16);
}
__device__ __forceinline__ float aload(const float* p) {
    return __hip_atomic_load((float*)p, __ATOMIC_RELAXED, __HIP_MEMORY_SCOPE_AGENT);
}
__device__ __forceinline__ void astore(float* p, float v) {
    __hip_atomic_store(p, v, __ATOMIC_RELAXED, __HIP_MEMORY_SCOPE_AGENT);
}

// ---------------------------------------------------------------- 0) weight preconvert
// LDS-tiled transpose (64x64 tiles, [64][65] padding): both global sides
// coalesced. 476 blocks. hi+lo planes; We2T col-permute folded into row map.
__global__ void __launch_bounds__(256) preconv_kernel(
    const float* __restrict__ Wc1, const float* __restrict__ Wc2,
    const float* __restrict__ Wc3, const float* __restrict__ We1,
    const float* __restrict__ We2, const float* __restrict__ Wf12,
    const float* __restrict__ Wf22,
    unsigned short* __restrict__ W1T, unsigned short* __restrict__ W2T,
    unsigned short* __restrict__ W3T, unsigned short* __restrict__ We1T,
    unsigned short* __restrict__ We2T, unsigned short* __restrict__ Wf12T,
    unsigned short* __restrict__ Wf22T) {
    __shared__ float tile[64][65];
    int bid = blockIdx.x, t = threadIdx.x;
    int tx = t & 63, ty = t >> 6;
    const float* src; unsigned short* dst;
    int Nsrc, Kout, validK, S, tn, tk; bool we2 = false;
    if (bid < 2)        { src=Wc1;  dst=W1T;  Nsrc=64;   Kout=96;  validK=67;  S=6144;    tn=0;     tk=bid; }
    else if (bid < 4)   { src=Wc2;  dst=W2T;  Nsrc=128;  Kout=64;  validK=64;  S=8192;    tn=bid-2; tk=0; }
    else if (bid < 20)  { int j=bid-4;   src=Wc3;  dst=W3T;  Nsrc=512;  Kout=128; validK=128; S=65536;   tn=j>>1; tk=j&1; }
    else if (bid < 92)  { int j=bid-20;  src=We1;  dst=We1T; Nsrc=512;  Kout=576; validK=515; S=294912;  tn=j/9;  tk=j-(j/9)*9; }
    else if (bid < 348) { int j=bid-92;  src=We2;  dst=We2T; Nsrc=2048; Kout=512; validK=512; S=1048576; tn=j>>3; tk=j&7; we2=true; }
    else if (bid < 412) { int j=bid-348; src=Wf12; dst=Wf12T;Nsrc=512;  Kout=512; validK=512; S=262144;  tn=j>>3; tk=j&7; }
    else                { int j=bid-412; src=Wf22; dst=Wf22T;Nsrc=512;  Kout=512; validK=512; S=262144;  tn=j>>3; tk=j&7; }
    int k0 = tk << 6, n0 = tn << 6;
    int m = we2 ? ((tx < 32) ? (n0 >> 1) + tx : 1024 + (n0 >> 1) + (tx - 32))
                : (n0 + tx);
#pragma unroll
    for (int r = 0; r < 16; ++r) {
        int k = k0 + ty * 16 + r;
        float v = (k < validK) ? src[(size_t)k * Nsrc + m] : 0.f;
        tile[ty * 16 + r][tx] = v;
    }
    __syncthreads();
    int k = k0 + tx;
    if (k < Kout) {
#pragma unroll
        for (int r = 0; r < 16; ++r) {
            int c = ty * 16 + r;
            int nrow = we2 ? (n0 + ((c < 32) ? 2 * c : 2 * (c - 32) + 1)) : (n0 + c);
            float v = tile[tx][c];
            unsigned short h, l; f2bf2(v, h, l);
            size_t o = (size_t)nrow * Kout + k;
            dst[o] = h; dst[S + o] = l;
        }
    }
}

// ---------------------------------------------------------------- stage1 (2392 blocks):
//  [0,8)        fps -> prog[b]
//  [8,2056)     pc consumers (forward s) -> encin + cnts[150+rb]
//  [2056,2120)  e1 (waits cnts[150+rb]==128) -> e1h + cnts[rb]
//  [2120,2376)  e2v (waits cnts[rb]==4) -> zacc atomics + cnts[16]
//  [2376,2392)  ukern (waits cnts[16]==256) -> u1/u2 via astore
__global__ void __launch_bounds__(256, 3) stage1_kernel(
    const float* __restrict__ pos, float* __restrict__ newpos, int* __restrict__ prog,
    int* __restrict__ cnts,
    const float* __restrict__ Wt, const float* __restrict__ bt,
    const unsigned short* __restrict__ W1T, const unsigned short* __restrict__ W2T,
    const unsigned short* __restrict__ W3T,
    const float* __restrict__ bc1, const float* __restrict__ bc2, const float* __restrict__ bc3,
    unsigned short* __restrict__ encin,
    const unsigned short* __restrict__ We1T, const float* __restrict__ be1,
    unsigned short* __restrict__ e1h,
    const unsigned short* __restrict__ We2T, const float* __restrict__ be2,
    float* __restrict__ zacc,
    const float* __restrict__ Wf11, const float* __restrict__ bf11,
    const float* __restrict__ Wf21, const float* __restrict__ bf21,
    float* __restrict__ u1, float* __restrict__ u2) {
    __shared__ __align__(16) unsigned char smem[53760];
    int blk = blockIdx.x, t = threadIdx.x;
    int wave = t >> 6, lane = t & 63;
    int quad = lane >> 4, l16 = lane & 15;

    if (blk < 8) {
        // ================= FPS producer (DPP-reduce version) =================
        float* pxs = (float*)smem;
        float* pys = (float*)(smem + 16384);
        float* pzs = (float*)(smem + 32768);
        float* npb = (float*)(smem + 49152);
        unsigned long long* rk = (unsigned long long*)(smem + 52224);
        int b = blk;
        const float* P = pos + (size_t)b * NPTS * 3;
        float* np = newpos + (size_t)b * SSAMP * 3;
        float px[16], py[16], pz[16], mind[16];
#pragma unroll
        for (int j = 0; j < 16; ++j) {
            int n = t + 256 * j;
            float X = P[n * 3 + 0], Y = P[n * 3 + 1], Z = P[n * 3 + 2];
            px[j] = X; py[j] = Y; pz[j] = Z;
            pxs[n] = X; pys[n] = Y; pzs[n] = Z;
            mind[j] = 3.402823466e+38f;
        }
        float cx = P[0], cy = P[1], cz = P[2];
        if (t == 0) { npb[0] = cx; npb[1] = cy; npb[2] = cz; }
        __syncthreads();
        for (int s = 1; s < SSAMP; ++s) {
            int p = s & 1;
            unsigned long long k[16];
#pragma unroll
            for (int j = 0; j < 16; ++j) {
                float dx = __fsub_rn(px[j], cx), dy = __fsub_rn(py[j], cy), dz = __fsub_rn(pz[j], cz);
                float d = __fadd_rn(__fadd_rn(__fmul_rn(dx, dx), __fmul_rn(dy, dy)), __fmul_rn(dz, dz));
                mind[j] = fminf(mind[j], d);
                k[j] = ((unsigned long long)__float_as_uint(mind[j]) << 32)
                     | (unsigned)~(unsigned)(t + 256 * j);
            }
#pragma unroll
            for (int st = 8; st > 0; st >>= 1)
#pragma unroll
                for (int j = 0; j < st; ++j) k[j] = umax64(k[j], k[j + st]);
            unsigned khi = (unsigned)(k[0] >> 32), klo = (unsigned)k[0];
#define FPS_DPP_STEP(CTRL)                                                                 \
            {                                                                              \
                unsigned h2 = (unsigned)__builtin_amdgcn_update_dpp(0, (int)khi, CTRL, 0xF, 0xF, true); \
                unsigned l2 = (unsigned)__builtin_amdgcn_update_dpp(0, (int)klo, CTRL, 0xF, 0xF, true); \
                bool tk = (h2 > khi) || ((h2 == khi) && (l2 > klo));                       \
                khi = tk ? h2 : khi; klo = tk ? l2 : klo;                                  \
            }
            FPS_DPP_STEP(0xB1)
            FPS_DPP_STEP(0x4E)
            FPS_DPP_STEP(0x141)
            FPS_DPP_STEP(0x140)
            FPS_DPP_STEP(0x142)
            FPS_DPP_STEP(0x143)
#undef FPS_DPP_STEP
            unsigned shi = (unsigned)__builtin_amdgcn_readlane((int)khi, 63);
            unsigned slo = (unsigned)__builtin_amdgcn_readlane((int)klo, 63);
            if (lane == 0) rk[p * 4 + wave] = ((unsigned long long)shi << 32) | slo;
            __syncthreads();
            unsigned long long k0 = rk[p * 4 + 0], k1 = rk[p * 4 + 1];
            unsigned long long k2 = rk[p * 4 + 2], k3 = rk[p * 4 + 3];
            unsigned long long bk = umax64(umax64(k0, k1), umax64(k2, k3));
            int nx = (int)(~(unsigned)(bk & 0xFFFFFFFFull));
            cx = pxs[nx]; cy = pys[nx]; cz = pzs[nx];
            if (t == 0) {
                npb[s * 3 + 0] = cx;
                npb[s * 3 + 1] = cy;
                npb[s * 3 + 2] = cz;
            }
            if ((s & 7) == 7) {
                if (t < 24) astore(&np[(s - 7) * 3 + t], npb[(s - 7) * 3 + t]);
                if (t == 0 && s >= 15)
                    __hip_atomic_store(&prog[b], s - 8, __ATOMIC_RELAXED, __HIP_MEMORY_SCOPE_AGENT);
            }
        }
        __syncthreads();
        if (t == 0)
            __hip_atomic_store(&prog[b], 255, __ATOMIC_RELAXED, __HIP_MEMORY_SCOPE_AGENT);
        return;
    }

    if (blk < 2056) {
        // ================= pointconv consumer (b,s) =================
        unsigned short* featl = (unsigned short*)smem;
        unsigned short* h2    = (unsigned short*)smem;
        unsigned short* h1    = (unsigned short*)(smem + 34816);
        float* mred = (float*)(smem + 34816);
        int*   vld  = (int*)(smem + 53248);
        int*   wl   = (int*)smem;
        int*   cnt  = (int*)(smem + 2048);
        float* wtb  = (float*)(smem + 26624);

        int cons = blk - 8;
        int s = cons >> 3, b = cons & 7;
        int bs = b * 256 + s;

        if (t == 0) spin_ge(&prog[b], s);
        __syncthreads();
        float q0 = aload(&newpos[(size_t)bs * 3 + 0]);
        float q1 = aload(&newpos[(size_t)bs * 3 + 1]);
        float q2 = aload(&newpos[(size_t)bs * 3 + 2]);

        const float* P = pos + (size_t)b * NPTS * 3;
        {
            int base = 0;
            for (int c = 0; c < 16 && base < KNBR; ++c) {
                int n = wave * 1024 + c * 64 + lane;
                float dx = __fsub_rn(P[n * 3 + 0], q0);
                float dy = __fsub_rn(P[n * 3 + 1], q1);
                float dz = __fsub_rn(P[n * 3 + 2], q2);
                float d2 = __fadd_rn(__fadd_rn(__fmul_rn(dx, dx), __fmul_rn(dy, dy)), __fmul_rn(dz, dz));
                bool in = (d2 <= 0.04f);
                unsigned long long mask = __ballot(in);
                if (in) {
                    int p = base + __popcll(mask & ((1ull << lane) - 1ull));
                    if (p < KNBR) wl[wave * 128 + p] = n;
                }
                base += __popcll(mask);
            }
            if (lane == 0) cnt[wave] = base < KNBR ? base : KNBR;
        }
        __syncthreads();
        {
            int c0 = cnt[0], c1 = cnt[1], c2 = cnt[2], c3 = cnt[3];
            if (t < 128) {
                int idx = -1, r = t;
                if (r < c0) idx = wl[r];
                else {
                    r -= c0;
                    if (r < c1) idx = wl[128 + r];
                    else {
                        r -= c1;
                        if (r < c2) idx = wl[256 + r];
                        else { r -= c2; if (r < c3) idx = wl[384 + r]; }
                    }
                }
                vld[t] = idx;
            }
            if (t < 192) wtb[t] = Wt[t];
            else wtb[t] = bt[t - 192];
        }
        __syncthreads();

        int vbits = 0;
#pragma unroll
        for (int i = 0; i < 2; ++i)
#pragma unroll
            for (int reg = 0; reg < 4; ++reg)
                if (vld[(2 * wave + i) * 16 + quad * 4 + reg] >= 0) vbits |= 1 << (i * 4 + reg);

        {
            int sr = t >> 1, sh = t & 1;
            int n = vld[sr];
            int ns = n < 0 ? 0 : n;
            const float* pp = pos + ((size_t)b * NPTS + ns) * 3;
            float p0 = pp[0], p1 = pp[1], p2 = pp[2];
            unsigned short* frow = &featl[sr * 104];
            u16x8 z8 = {0, 0, 0, 0, 0, 0, 0, 0};
            if (n >= 0) {
#pragma unroll
                for (int g = 0; g < 4; ++g) {
                    u16x8 v8;
#pragma unroll
                    for (int e = 0; e < 8; ++e) {
                        int c = sh * 32 + g * 8 + e;
                        float v = fmaf(p2, wtb[128 + c], fmaf(p1, wtb[64 + c], fmaf(p0, wtb[c], wtb[192 + c])));
                        v8[e] = (unsigned short)f2bf(lrelu01(v));
                    }
                    *(u16x8*)&frow[sh * 32 + g * 8] = v8;
                }
            } else {
#pragma unroll
                for (int g = 0; g < 4; ++g) *(u16x8*)&frow[sh * 32 + g * 8] = z8;
            }
            if (sh == 1) {
                u16x8 dv = z8;
                if (n >= 0) {
                    dv[0] = (unsigned short)f2bf(__fsub_rn(p0, q0));
                    dv[1] = (unsigned short)f2bf(__fsub_rn(p1, q1));
                    dv[2] = (unsigned short)f2bf(__fsub_rn(p2, q2));
                }
                *(u16x8*)&frow[64] = dv;
                *(u16x8*)&frow[72] = z8;
                *(u16x8*)&frow[80] = z8;
                *(u16x8*)&frow[88] = z8;
            }
        }
        __syncthreads();

        {
            f32x4 acc[2][4];
#pragma unroll
            for (int i = 0; i < 2; ++i)
#pragma unroll
                for (int nt = 0; nt < 4; ++nt) acc[i][nt] = (f32x4){0.f, 0.f, 0.f, 0.f};
#pragma unroll
            for (int ks = 0; ks < 3; ++ks) {
                bf16x8 afr[2];
#pragma unroll
                for (int i = 0; i < 2; ++i)
                    afr[i] = *(const bf16x8*)&featl[((2 * wave + i) * 16 + l16) * 104 + ks * 32 + quad * 8];
#pragma unroll
                for (int nt = 0; nt < 4; ++nt) {
                    const unsigned short* wp = W1T + (nt * 16 + l16) * 96 + ks * 32 + quad * 8;
                    bf16x8 bh = *(const bf16x8*)wp;
                    bf16x8 bl = *(const bf16x8*)(wp + 6144);
                    acc[0][nt] = MFMA16(afr[0], bh, acc[0][nt]);
                    acc[1][nt] = MFMA16(afr[1], bh, acc[1][nt]);
                    acc[0][nt] = MFMA16(afr[0], bl, acc[0][nt]);
                    acc[1][nt] = MFMA16(afr[1], bl, acc[1][nt]);
                }
            }
#pragma unroll
            for (int i = 0; i < 2; ++i)
#pragma unroll
                for (int nt = 0; nt < 4; ++nt) {
                    int col = nt * 16 + l16;
                    float bias = bc1[col];
#pragma unroll
                    for (int reg = 0; reg < 4; ++reg) {
                        int row = (2 * wave + i) * 16 + quad * 4 + reg;
                        h1[row * 72 + col] = f2bf(lrelu01(acc[i][nt][reg] + bias));
                    }
                }
        }
        __syncthreads();

        {
            f32x4 acc[2][8];
#pragma unroll
            for (int i = 0; i < 2; ++i)
#pragma unroll
                for (int nt = 0; nt < 8; ++nt) acc[i][nt] = (f32x4){0.f, 0.f, 0.f, 0.f};
#pragma unroll
            for (int ks = 0; ks < 2; ++ks) {
                bf16x8 afr[2];
#pragma unroll
                for (int i = 0; i < 2; ++i)
                    afr[i] = *(const bf16x8*)&h1[((2 * wave + i) * 16 + l16) * 72 + ks * 32 + quad * 8];
#pragma unroll
                for (int nt = 0; nt < 8; ++nt) {
                    const unsigned short* wp = W2T + (nt * 16 + l16) * 64 + ks * 32 + quad * 8;
                    bf16x8 bh = *(const bf16x8*)wp;
                    bf16x8 bl = *(const bf16x8*)(wp + 8192);
                    acc[0][nt] = MFMA16(afr[0], bh, acc[0][nt]);
                    acc[1][nt] = MFMA16(afr[1], bh, acc[1][nt]);
                    acc[0][nt] = MFMA16(afr[0], bl, acc[0][nt]);
                    acc[1][nt] = MFMA16(afr[1], bl, acc[1][nt]);
                }
            }
            __syncthreads();
#pragma unroll
            for (int i = 0; i < 2; ++i)
#pragma unroll
                for (int nt = 0; nt < 8; ++nt) {
                    int col = nt * 16 + l16;
                    float bias = bc2[col];
#pragma unroll
                    for (int reg = 0; reg < 4; ++reg) {
                        int row = (2 * wave + i) * 16 + quad * 4 + reg;
                        h2[row * 136 + col] = f2bf(lrelu01(acc[i][nt][reg] + bias));
                    }
                }
        }
        __syncthreads();

        for (int c3 = 0; c3 < 4; ++c3) {
            f32x4 acc[2][8];
#pragma unroll
            for (int i = 0; i < 2; ++i)
#pragma unroll
                for (int nt = 0; nt < 8; ++nt) acc[i][nt] = (f32x4){0.f, 0.f, 0.f, 0.f};
#pragma unroll
            for (int ks = 0; ks < 4; ++ks) {
                bf16x8 afr[2];
#pragma unroll
                for (int i = 0; i < 2; ++i)
                    afr[i] = *(const bf16x8*)&h2[((2 * wave + i) * 16 + l16) * 136 + ks * 32 + quad * 8];
#pragma unroll
                for (int nt = 0; nt < 8; ++nt) {
                    const unsigned short* wp = W3T + ((size_t)((c3 * 8 + nt) * 16 + l16)) * 128 + ks * 32 + quad * 8;
                    bf16x8 bh = *(const bf16x8*)wp;
                    bf16x8 bl = *(const bf16x8*)(wp + 65536);
                    acc[0][nt] = MFMA16(afr[0], bh, acc[0][nt]);
                    acc[1][nt] = MFMA16(afr[1], bh, acc[1][nt]);
                    acc[0][nt] = MFMA16(afr[0], bl, acc[0][nt]);
                    acc[1][nt] = MFMA16(afr[1], bl, acc[1][nt]);
                }
            }
#pragma unroll
            for (int nt = 0; nt < 8; ++nt) {
                float vmax = -3.402823466e+38f;
#pragma unroll
                for (int i = 0; i < 2; ++i)
#pragma unroll
                    for (int reg = 0; reg < 4; ++reg)
                        if (vbits & (1 << (i * 4 + reg))) vmax = fmaxf(vmax, acc[i][nt][reg]);
                vmax = fmaxf(vmax, __shfl_xor(vmax, 16));
                vmax = fmaxf(vmax, __shfl_xor(vmax, 32));
                if (lane < 16) mred[wave * 512 + (c3 * 8 + nt) * 16 + l16] = vmax;
            }
        }
        __syncthreads();
        unsigned short* erow = encin + (size_t)bs * 576;
        for (int c = t; c < 576; c += 256) {
            unsigned short v;
            if (c < 512) {
                float m4 = fmaxf(fmaxf(mred[c], mred[512 + c]), fmaxf(mred[1024 + c], mred[1536 + c]));
                v = f2bf(lrelu01(m4 + bc3[c]));
            } else if (c < 515) {
                v = f2bf(c == 512 ? q0 : (c == 513 ? q1 : q2));
            } else v = 0;
            erow[c] = v;
        }
        __syncthreads();
        if (t == 0) { __threadfence(); atomicAdd(&cnts[150 + (bs >> 7)], 1); }
        return;
    }

    if (blk < 2376) {
        // ================= e1 (2056..2120) / e2v (2120..2376) =================
        unsigned short* As = (unsigned short*)smem;
        bool is_e1 = blk < 2120;
        int rb, cb;
        const unsigned short* A;
        const unsigned short* BT;
        int Ka;
        if (is_e1) {
            int j = blk - 2056; rb = j >> 2; cb = j & 3; A = encin; BT = We1T; Ka = 576;
            if (t == 0) spin_ge(&cnts[150 + rb], 128);
        } else {
            int j = blk - 2120; rb = j >> 4; cb = j & 15; A = e1h; BT = We2T; Ka = 512;
            if (t == 0) spin_ge(&cnts[rb], 4);
        }
        int bofs = is_e1 ? 294912 : 1048576;   // lo-plane offset (elements)
        __syncthreads();
        __threadfence();   // acquire bulk normal-store data (encin / e1h)
        int row0 = rb * 128, col0 = cb * 128;
        f32x4 acc[2][8];
#pragma unroll
        for (int i = 0; i < 2; ++i)
#pragma unroll
            for (int nt = 0; nt < 8; ++nt) acc[i][nt] = (f32x4){0.f, 0.f, 0.f, 0.f};
        int nk = Ka >> 6;
        int sr = t >> 1, sh = t & 1;
        const unsigned short* Arow = A + (size_t)(row0 + sr) * Ka + sh * 32;
        for (int ks = 0; ks < nk; ++ks) {
            u16x8 av[4];
#pragma unroll
            for (int j2 = 0; j2 < 4; ++j2) av[j2] = *(const u16x8*)(Arow + ks * 64 + j2 * 8);
            __syncthreads();
#pragma unroll
            for (int j2 = 0; j2 < 4; ++j2) *(u16x8*)&As[sr * 72 + sh * 32 + j2 * 8] = av[j2];
            __syncthreads();
#pragma unroll
            for (int ks2 = 0; ks2 < 2; ++ks2) {
                bf16x8 afr0 = *(const bf16x8*)&As[((2 * wave) * 16 + l16) * 72 + ks2 * 32 + quad * 8];
                bf16x8 afr1 = *(const bf16x8*)&As[((2 * wave + 1) * 16 + l16) * 72 + ks2 * 32 + quad * 8];
#pragma unroll
                for (int nt = 0; nt < 8; ++nt) {
                    const unsigned short* wp = BT + (size_t)(col0 + nt * 16 + l16) * Ka + ks * 64 + ks2 * 32 + quad * 8;
                    bf16x8 bh = *(const bf16x8*)wp;
                    bf16x8 bl = *(const bf16x8*)(wp + bofs);
                    acc[0][nt] = MFMA16(afr0, bh, acc[0][nt]);
                    acc[1][nt] = MFMA16(afr1, bh, acc[1][nt]);
                    acc[0][nt] = MFMA16(afr0, bl, acc[0][nt]);
                    acc[1][nt] = MFMA16(afr1, bl, acc[1][nt]);
                }
            }
        }
        if (is_e1) {
#pragma unroll
            for (int i = 0; i < 2; ++i)
#pragma unroll
                for (int nt = 0; nt < 8; ++nt) {
                    int col = col0 + nt * 16 + l16;
                    float bv = be1[col];
#pragma unroll
                    for (int reg = 0; reg < 4; ++reg) {
                        int row = row0 + (2 * wave + i) * 16 + quad * 4 + reg;
                        e1h[(size_t)row * 512 + col] = f2bf(lrelu01(acc[i][nt][reg] + bv));
                    }
                }
            __syncthreads();
            if (t == 0) { __threadfence(); atomicAdd(&cnts[rb], 1); }
        } else {
            int b = row0 >> 8;
#pragma unroll
            for (int nt = 0; nt < 8; ++nt) {
                int colp = col0 + nt * 16 + l16;
                int c2 = colp >> 1;
                int srcc = (colp & 1) ? 1024 + c2 : c2;
                float bv = be2[srcc];
                float num = 0.f, den = 0.f;
#pragma unroll
                for (int i = 0; i < 2; ++i)
#pragma unroll
                    for (int reg = 0; reg < 4; ++reg) {
                        float val = acc[i][nt][reg] + bv;
                        float par = __shfl_xor(val, 1, 64);
                        float d = expf(-0.5f * par);
                        num += val * d;
                        den += d;
                    }
                num += __shfl_xor(num, 16, 64); den += __shfl_xor(den, 16, 64);
                num += __shfl_xor(num, 32, 64); den += __shfl_xor(den, 32, 64);
                if (quad == 0 && !(l16 & 1)) {
                    atomicAdd(&zacc[((b << 10) + c2) * 2 + 0], num);
                    atomicAdd(&zacc[((b << 10) + c2) * 2 + 1], den);
                }
            }
            __syncthreads();
            if (t == 0) atomicAdd(&cnts[16], 1);
        }
        return;
    }

    // ================= ukern (2376..2392) =================
    {
        float* zt = (float*)smem;
        float* red = (float*)(smem + 32768);
        int j = blk - 2376;
        int dec = j >> 3, cb = j & 7;
        const float* W = dec ? Wf21 : Wf11;
        const float* bias = dec ? bf21 : bf11;
        float* u = dec ? u2 : u1;
        if (t == 0) spin_ge(&cnts[16], 256);
        __syncthreads();
#pragma unroll
        for (int i = 0; i < 32; ++i) {
            int o = t + i * 256;
            float num = aload(&zacc[o * 2 + 0]);
            float den = aload(&zacc[o * 2 + 1]);
            zt[(o & 1023) * 8 + (o >> 10)] = num / den;
        }
        __syncthreads();
        int c64 = t & 63, kc = t >> 6;
        int co = cb * 64 + c64;
        float acc[8];
#pragma unroll
        for (int r = 0; r < 8; ++r) acc[r] = 0.f;
        for (int i = 0; i < 256; ++i) {
            int ci = kc * 256 + i;
            float w = W[(size_t)ci * 512 + co];
            const float4* zp = (const float4*)&zt[ci * 8];
            float4 z0 = zp[0], z1 = zp[1];
            acc[0] = fmaf(z0.x, w, acc[0]); acc[1] = fmaf(z0.y, w, acc[1]);
            acc[2] = fmaf(z0.z, w, acc[2]); acc[3] = fmaf(z0.w, w, acc[3]);
            acc[4] = fmaf(z1.x, w, acc[4]); acc[5] = fmaf(z1.y, w, acc[5]);
            acc[6] = fmaf(z1.z, w, acc[6]); acc[7] = fmaf(z1.w, w, acc[7]);
        }
#pragma unroll
        for (int r = 0; r < 8; ++r) red[(kc * 64 + c64) * 8 + r] = acc[r];
        __syncthreads();
        if (kc == 0) {
#pragma unroll
            for (int r = 0; r < 8; ++r) {
                float v = red[(0 * 64 + c64) * 8 + r] + red[(1 * 64 + c64) * 8 + r]
                        + red[(2 * 64 + c64) * 8 + r] + red[(3 * 64 + c64) * 8 + r] + bias[co];
                astore(&u[r * 512 + co], v);
            }
        }
    }
}

// ---------------------------------------------------------------- tail: folds only, 1016 blocks.
// [0,508) ff1 (j,cc): NO spin (u1 ready by stream order) -> pts atomics + cnts[20+j];
// [508,1016) ff2 (j,cc): waits cnts[20+j]==4 -> out atomics.
// WT weight fragments are PREFETCHED into registers at the top of each ks
// iteration: R10 counters showed the fold phase latency-bound (VALU 10%,
// MFMA 7%, HBM 0.6%) on the 32 scattered L2 loads feeding the MFMAs. The
// prefetch drains that latency under the barrier + As/Asl fill VALU.
__global__ void __launch_bounds__(256, 2) tail_kernel(
    int* __restrict__ cnts,
    const float* __restrict__ Wf11, const float* __restrict__ Wf21,
    const float* __restrict__ u1, const float* __restrict__ u2,
    const unsigned short* __restrict__ Wf12T, const float* __restrict__ bf12,
    const float* __restrict__ Wf13, const float* __restrict__ bf13,
    const unsigned short* __restrict__ Wf22T, const float* __restrict__ bf22,
    const float* __restrict__ Wf23, const float* __restrict__ bf23,
    float* __restrict__ pts, float* __restrict__ outv) {
    __shared__ __align__(16) unsigned char smem[59392];
    int blk = blockIdx.x, t = threadIdx.x;
    int wave = t >> 6, lane = t & 63, quad = lane >> 4, l16 = lane & 15;

    unsigned short* As = (unsigned short*)smem;          // 18432 (hi)
    float* sW = (float*)(smem + 18432);                  // [3][512]
    float* sU = (float*)(smem + 24576);                  // [2][512]
    float* sP = (float*)(smem + 28672);                  // [128*3]
    float* sB = (float*)(smem + 30208);                  // [128]
    float* sRC = (float*)(smem + 30720);                 // [128][4]
    unsigned short* Asl = (unsigned short*)(smem + 40960); // 18432 (lo)
    int dec = blk < 508 ? 0 : 1;
    int idx0 = blk - (dec ? 508 : 0);
    int j = idx0 >> 2, cc = idx0 & 3;
    const float* u = dec ? u2 : u1;
    const float* Wfold = dec ? Wf21 : Wf11;
    int nExtra = dec ? 3 : 2;
    const unsigned short* WT = dec ? Wf22T : Wf12T;
    const float* bmid = dec ? bf22 : bf12;
    const float* wout = dec ? Wf23 : Wf13;
    const float* bout = dec ? bf23 : bf13;
    float* ov = dec ? outv : pts;
    int row0 = j * 128, col0 = cc * 128;
    int b0 = row0 / 2025;

    // static preloads (before any spin)
    for (int idx = t; idx < 1536; idx += 256) {
        int r = idx >> 9, c = idx & 511;
        sW[r * 512 + c] = (r < nExtra) ? Wfold[(size_t)(1024 + r) * 512 + c] : 0.f;
    }
    for (int idx = t; idx < 384; idx += 256) sP[idx] = wout[col0 * 3 + idx];
    if (t < 128) sB[t] = bmid[col0 + t];
    for (int idx = t; idx < 1024; idx += 256) {
        int rb = idx >> 9;
        int bb = b0 + rb; if (bb > 7) bb = 7;
        sU[rb * 512 + (idx & 511)] = aload(&u[bb * 512 + (idx & 511)]);
    }
    if (dec == 0 && t < 128) {
        int rg = row0 + t; if (rg > 16199) rg = 16199;
        int b = rg / 2025, g = rg - b * 2025;
        int i = g / 45, jj = g - i * 45;
        sRC[t * 4 + 0] = (jj == 44) ? 0.3f : (float)(-0.3 + jj * (0.6 / 44.0));
        sRC[t * 4 + 1] = (i == 44) ? 0.3f : (float)(-0.3 + i * (0.6 / 44.0));
        sRC[t * 4 + 2] = 0.f;
        sRC[t * 4 + 3] = __int_as_float(b - b0);
    }

    if (dec) {
        if (t == 0) spin_ge(&cnts[20 + j], 4);
        __syncthreads();
        if (t < 128) {
            int rg = row0 + t; if (rg > 16199) rg = 16199;
            int b = rg / 2025;
            sRC[t * 4 + 0] = aload(&pts[rg * 3 + 0]);
            sRC[t * 4 + 1] = aload(&pts[rg * 3 + 1]);
            sRC[t * 4 + 2] = aload(&pts[rg * 3 + 2]);
            sRC[t * 4 + 3] = __int_as_float(b - b0);
        }
    }
    __syncthreads();

    float proj[2][4][3];
#pragma unroll
    for (int i = 0; i < 2; ++i)
#pragma unroll
        for (int r = 0; r < 4; ++r) { proj[i][r][0] = 0.f; proj[i][r][1] = 0.f; proj[i][r][2] = 0.f; }

    int sr = t >> 1, sh = t & 1;
    float4 rc = *(const float4*)&sRC[sr * 4];
    int ubi = __float_as_int(rc.w);
    const float* up = sU + ubi * 512;
    f32x4 acc[2][8];
#pragma unroll
    for (int i = 0; i < 2; ++i)
#pragma unroll
        for (int nt = 0; nt < 8; ++nt) acc[i][nt] = (f32x4){0.f, 0.f, 0.f, 0.f};
    for (int ks = 0; ks < 8; ++ks) {
        // -------- prefetch this ks's 32 weight fragments (L2 latency drains
        // under barrier-wait + fill VALU; fully static indices -> registers)
        bf16x8 wbh[16], wbl[16];
#pragma unroll
        for (int ks2 = 0; ks2 < 2; ++ks2)
#pragma unroll
            for (int nt = 0; nt < 8; ++nt) {
                const unsigned short* wp = WT + (size_t)(col0 + nt * 16 + l16) * 512 + ks * 64 + ks2 * 32 + quad * 8;
                wbh[ks2 * 8 + nt] = *(const bf16x8*)wp;
                wbl[ks2 * 8 + nt] = *(const bf16x8*)(wp + 262144);
            }
        __syncthreads();
        {
            int cbase = ks * 64 + sh * 32;
            const float4* w0p = (const float4*)&sW[cbase];
            const float4* w1p = (const float4*)&sW[512 + cbase];
            const float4* w2p = (const float4*)&sW[1024 + cbase];
            const float4* uup = (const float4*)&up[cbase];
#pragma unroll
            for (int g4 = 0; g4 < 8; ++g4) {
                float4 w0 = w0p[g4], w1 = w1p[g4], w2 = w2p[g4], uu = uup[g4];
                float v0 = fmaf(rc.z, w2.x, fmaf(rc.y, w1.x, fmaf(rc.x, w0.x, uu.x)));
                float v1 = fmaf(rc.z, w2.y, fmaf(rc.y, w1.y, fmaf(rc.x, w0.y, uu.y)));
                float v2 = fmaf(rc.z, w2.z, fmaf(rc.y, w1.z, fmaf(rc.x, w0.z, uu.z)));
                float v3 = fmaf(rc.z, w2.w, fmaf(rc.y, w1.w, fmaf(rc.x, w0.w, uu.w)));
                float r0 = fmaxf(v0, 0.f), r1 = fmaxf(v1, 0.f);
                float r2 = fmaxf(v2, 0.f), r3 = fmaxf(v3, 0.f);
                unsigned short h0, l0, h1s, l1s, h2s, l2s, h3s, l3s;
                f2bf2(r0, h0, l0); f2bf2(r1, h1s, l1s);
                f2bf2(r2, h2s, l2s); f2bf2(r3, h3s, l3s);
                uint2 pkh, pkl;
                pkh.x = (unsigned)h0 | ((unsigned)h1s << 16);
                pkh.y = (unsigned)h2s | ((unsigned)h3s << 16);
                pkl.x = (unsigned)l0 | ((unsigned)l1s << 16);
                pkl.y = (unsigned)l2s | ((unsigned)l3s << 16);
                *(uint2*)&As[sr * 72 + sh * 32 + g4 * 4] = pkh;
                *(uint2*)&Asl[sr * 72 + sh * 32 + g4 * 4] = pkl;
            }
        }
        __syncthreads();
#pragma unroll
        for (int ks2 = 0; ks2 < 2; ++ks2) {
            bf16x8 ah0 = *(const bf16x8*)&As[((2 * wave) * 16 + l16) * 72 + ks2 * 32 + quad * 8];
            bf16x8 ah1 = *(const bf16x8*)&As[((2 * wave + 1) * 16 + l16) * 72 + ks2 * 32 + quad * 8];
            bf16x8 al0 = *(const bf16x8*)&Asl[((2 * wave) * 16 + l16) * 72 + ks2 * 32 + quad * 8];
            bf16x8 al1 = *(const bf16x8*)&Asl[((2 * wave + 1) * 16 + l16) * 72 + ks2 * 32 + quad * 8];
#pragma unroll
            for (int nt = 0; nt < 8; ++nt) {
                bf16x8 bh = wbh[ks2 * 8 + nt];
                bf16x8 bl = wbl[ks2 * 8 + nt];
                acc[0][nt] = MFMA16(ah0, bh, acc[0][nt]);
                acc[1][nt] = MFMA16(ah1, bh, acc[1][nt]);
                acc[0][nt] = MFMA16(ah0, bl, acc[0][nt]);
                acc[1][nt] = MFMA16(ah1, bl, acc[1][nt]);
                acc[0][nt] = MFMA16(al0, bh, acc[0][nt]);
                acc[1][nt] = MFMA16(al1, bh, acc[1][nt]);
            }
        }
    }
#pragma unroll
    for (int i = 0; i < 2; ++i)
#pragma unroll
        for (int nt = 0; nt < 8; ++nt) {
            int lc = nt * 16 + l16;
            float bv = sB[lc];
            float w0 = sP[lc * 3 + 0], w1 = sP[lc * 3 + 1], w2 = sP[lc * 3 + 2];
#pragma unroll
            for (int reg = 0; reg < 4; ++reg) {
                float h = fmaxf(acc[i][nt][reg] + bv, 0.f);
                proj[i][reg][0] = fmaf(h, w0, proj[i][reg][0]);
                proj[i][reg][1] = fmaf(h, w1, proj[i][reg][1]);
                proj[i][reg][2] = fmaf(h, w2, proj[i][reg][2]);
            }
        }
    float o0 = (cc == 0) ? bout[0] : 0.f;
    float o1 = (cc == 0) ? bout[1] : 0.f;
    float o2 = (cc == 0) ? bout[2] : 0.f;
#pragma unroll
    for (int i = 0; i < 2; ++i)
#pragma unroll
        for (int reg = 0; reg < 4; ++reg) {
            float p0 = proj[i][reg][0], p1 = proj[i][reg][1], p2 = proj[i][reg][2];
#pragma unroll
            for (int m = 1; m < 16; m <<= 1) {
                p0 += __shfl_xor(p0, m, 64);
                p1 += __shfl_xor(p1, m, 64);
                p2 += __shfl_xor(p2, m, 64);
            }
            if (l16 == 0) {
                int row = row0 + (2 * wave + i) * 16 + quad * 4 + reg;
                if (row < 16200) {
                    atomicAdd(&ov[row * 3 + 0], p0 + o0);
                    atomicAdd(&ov[row * 3 + 1], p1 + o1);
                    atomicAdd(&ov[row * 3 + 2], p2 + o2);
                }
            }
        }
    if (dec == 0) {
        __syncthreads();
        if (t == 0) atomicAdd(&cnts[20 + j], 1);
    }
}

extern "C" void kernel_launch(void* const* d_in, const int* in_sizes, int n_in,
                              void* d_out, int out_size, void* d_ws, size_t ws_size,
                              hipStream_t stream) {
    const float* pos  = (const float*)d_in[0];
    const float* Wt   = (const float*)d_in[1];
    const float* bt   = (const float*)d_in[2];
    const float* Wc1  = (const float*)d_in[3];
    const float* bc1  = (const float*)d_in[4];
    const float* Wc2  = (const float*)d_in[5];
    const float* bc2  = (const float*)d_in[6];
    const float* Wc3  = (const float*)d_in[7];
    const float* bc3  = (const float*)d_in[8];
    const float* We1  = (const float*)d_in[9];
    const float* be1  = (const float*)d_in[10];
    const float* We2  = (const float*)d_in[11];
    const float* be2  = (const float*)d_in[12];
    const float* Wf11 = (const float*)d_in[13];
    const float* bf11 = (const float*)d_in[14];
    const float* Wf12 = (const float*)d_in[15];
    const float* bf12 = (const float*)d_in[16];
    const float* Wf13 = (const float*)d_in[17];
    const float* bf13 = (const float*)d_in[18];
    const float* Wf21 = (const float*)d_in[19];
    const float* bf21 = (const float*)d_in[20];
    const float* Wf22 = (const float*)d_in[21];
    const float* bf22 = (const float*)d_in[22];
    const float* Wf23 = (const float*)d_in[23];
    const float* bf23 = (const float*)d_in[24];
    float* out = (float*)d_out;

    float* wsf = (float*)d_ws;
    size_t off = 0;
    unsigned short* encinh= (unsigned short*)(wsf + off); off += 589824;   // [2048][576] bf16
    unsigned short* e1h   = (unsigned short*)(wsf + off); off += 524288;   // [2048][512] bf16
    float* zacc = wsf + off; off += 16384;     // [8][1024][2]
    float* u1   = wsf + off; off += 4096;
    float* u2   = wsf + off; off += 4096;
    float* pts  = wsf + off; off += 48600;     // [16200][3] (atomic-accumulated)
    float* newp = wsf + off; off += 6144;      // [B,S,3]
    int*   prog = (int*)(wsf + off); off += 16;
    int*   cnts = (int*)(wsf + off); off += 256;
    // weight planes doubled: hi at [0,N), lo at [N,2N) shorts -> N floats each
    unsigned short* W1T   = (unsigned short*)(wsf + off); off += 6144;
    unsigned short* W2T   = (unsigned short*)(wsf + off); off += 8192;
    unsigned short* W3T   = (unsigned short*)(wsf + off); off += 65536;
    unsigned short* We1T  = (unsigned short*)(wsf + off); off += 294912;
    unsigned short* We2T  = (unsigned short*)(wsf + off); off += 1048576;
    unsigned short* Wf12T = (unsigned short*)(wsf + off); off += 262144;
    unsigned short* Wf22T = (unsigned short*)(wsf + off); off += 262144;

    hipMemsetAsync(prog, 0xFF, 64, stream);
    hipMemsetAsync(cnts, 0x00, 1024, stream);
    hipMemsetAsync(zacc, 0x00, 16384 * 4, stream);
    hipMemsetAsync(pts, 0x00, 48600 * 4, stream);
    hipMemsetAsync(out, 0x00, (size_t)out_size * 4, stream);
    preconv_kernel<<<476, 256, 0, stream>>>(Wc1, Wc2, Wc3, We1, We2, Wf12, Wf22,
                                            W1T, W2T, W3T, We1T, We2T, Wf12T, Wf22T);
    stage1_kernel<<<2392, 256, 0, stream>>>(pos, newp, prog, cnts, Wt, bt, W1T, W2T, W3T,
                                            bc1, bc2, bc3, encinh,
                                            We1T, be1, e1h, We2T, be2, zacc,
                                            Wf11, bf11, Wf21, bf21, u1, u2);
    tail_kernel<<<1016, 256, 0, stream>>>(cnts, Wf11, Wf21, u1, u2,
                                          Wf12T, bf12, Wf13, bf13,
                                          Wf22T, bf22, Wf23, bf23, pts, out);
}